// Round 1
// 1162.695 us; speedup vs baseline: 1.0934x; 1.0934x over previous
//
#include <hip/hip_runtime.h>
#include <math.h>

#define BB 8
#define CC 256
#define HH 128
#define WW 128
#define NN (HH*WW)          // 16384
#define NBVEC 16
#define CSPLIT 4
#define CCHUNK (CC/CSPLIT)  // 64
#define NBX (NN/256)        // 64

// ---------------- workspace layout (bytes) ----------------
// score  double[B][N]          @ 0       : 1048576
// simbuf double[B][N]          @ 1048576 : 1048576
// d2part double[CSPLIT][B][N]  @ 2097152 : 4194304
// wsum   double[B][C]          @ 6291456 : 16384
// sumSim double[B]             @ 6307840 : 64
// rv     float [B][C]          @ 6307904 : 8192
// bmaxv  double[B][NBX]        @ 6316096 : 4096
// bmaxi  int   [B][NBX]        @ 6320192 : 2048
// total ~6.03 MB

// Control: one block per batch b, 256 threads.
//  - finalize previous iteration's reprVec = wsum / sumSim; reset sumSim
//  - pick index (N/2 at iter 0, else reduce the 64 per-block argmax partials
//    emitted by finish_kernel; first-occurrence tie-break preserved)
//  - selpos += 1 at index; gather rv[b][:] = x[b][:][ind]
__global__ void control_kernel(const float* __restrict__ x, float* __restrict__ out,
                               const double* __restrict__ bmaxv,
                               const int* __restrict__ bmaxi,
                               const double* __restrict__ wsum,
                               double* __restrict__ sumSim,
                               float* __restrict__ rv, int iter)
{
    const int b = blockIdx.x;
    const int t = threadIdx.x;   // 256 threads

    float* out_repr   = out;                                                // [NBVEC][B][C]
    float* out_selpos = out + (size_t)NBVEC*BB*CC + (size_t)NBVEC*BB*NN;    // [B][N]

    __shared__ double s_val[NBX];
    __shared__ int    s_idx[NBX];
    __shared__ int    s_ind;

    if (iter > 0) {
        double ss = sumSim[b];
        if (t < CC) {
            out_repr[(size_t)(iter-1)*BB*CC + (size_t)b*CC + t] =
                (float)(wsum[(size_t)b*CC + t] / ss);
        }
    }
    __syncthreads();
    if (t == 0) sumSim[b] = 0.0;

    if (iter >= NBVEC) return;   // last call only finalizes

    if (iter == 0) {
        if (t == 0) s_ind = NN/2;
    } else {
        if (t < NBX) { s_val[t] = bmaxv[b*NBX + t]; s_idx[t] = bmaxi[b*NBX + t]; }
        __syncthreads();
        for (int s = NBX/2; s > 0; s >>= 1) {
            if (t < s) {
                double v2 = s_val[t+s]; int i2 = s_idx[t+s];
                if (v2 > s_val[t] || (v2 == s_val[t] && i2 < s_idx[t])) {
                    s_val[t] = v2; s_idx[t] = i2;
                }
            }
            __syncthreads();
        }
        if (t == 0) s_ind = s_idx[0];
    }
    __syncthreads();

    const int sel = s_ind;
    if (t == 0) out_selpos[(size_t)b*NN + sel] += 1.0f;
    if (t < CC) rv[(size_t)b*CC + t] = x[(size_t)b*CC*NN + (size_t)t*NN + sel];
}

// Phase 1 (C-split): grid (N/256, CSPLIT, B), 256 threads; thread-per-n.
// Each block reduces a 64-channel slice: d2part[cz][b][n] = sum_c (x - rv)^2.
// 2048 blocks -> 32 waves/CU (was 512 blocks / 8 waves/CU: latency-bound).
// Same sequential fp64 fma order within each slice as the old kernel.
__global__ void phase1_kernel(const float* __restrict__ x,
                              const float* __restrict__ rv,
                              double* __restrict__ d2part)
{
    const int b  = blockIdx.z;
    const int cz = blockIdx.y;
    const int t  = threadIdx.x;
    const int n  = blockIdx.x * 256 + t;

    __shared__ float s_rv[CCHUNK];
    if (t < CCHUNK) s_rv[t] = rv[(size_t)b*CC + (size_t)cz*CCHUNK + t];
    __syncthreads();

    const float* xb = x + (size_t)b*CC*NN + (size_t)cz*CCHUNK*NN;
    double acc = 0.0;
    #pragma unroll 8
    for (int c = 0; c < CCHUNK; ++c) {
        double diff = (double)xb[(size_t)c*NN + n] - (double)s_rv[c];
        acc = fma(diff, diff, acc);
    }
    d2part[((size_t)cz*BB + b)*NN + n] = acc;
}

// Finisher: grid (N/256, B), 256 threads; thread-per-n.
// d2 = sum of 4 partials (fixed order), sim = exp(-sqrt(d2+1e-12)/20),
// write sim (ws fp64 + output fp32), score update, block-reduce sumSim,
// block-argmax partials for control.
__global__ void finish_kernel(float* __restrict__ out,
                              double* __restrict__ score,
                              double* __restrict__ simbuf,
                              const double* __restrict__ d2part,
                              double* __restrict__ sumSim,
                              double* __restrict__ bmaxv,
                              int* __restrict__ bmaxi, int iter)
{
    const int b = blockIdx.y;
    const int t = threadIdx.x;
    const int n = blockIdx.x * 256 + t;
    const size_t si = (size_t)b*NN + n;

    double d2 = ((d2part[((size_t)0*BB + b)*NN + n]
                + d2part[((size_t)1*BB + b)*NN + n])
                + d2part[((size_t)2*BB + b)*NN + n])
                + d2part[((size_t)3*BB + b)*NN + n];

    double d   = sqrt(d2 + 1e-12);
    double sim = exp(-(d / 20.0));

    simbuf[si] = sim;
    float* out_sims = out + (size_t)NBVEC*BB*CC;   // [NBVEC][B][N]
    out_sims[(size_t)iter*BB*NN + si] = (float)sim;

    double sc;
    if (iter == 0) sc = 1.0 - sim;
    else           sc = (1.0 - sim) * score[si];
    score[si] = sc;

    // block-reduce sumSim (same 256-n grouping as before -> identical partials)
    __shared__ double s_red[256];
    s_red[t] = sim;
    __syncthreads();
    for (int s = 128; s > 0; s >>= 1) {
        if (t < s) s_red[t] += s_red[t+s];
        __syncthreads();
    }
    if (t == 0) atomicAdd(&sumSim[b], s_red[0]);

    // block argmax of updated score (first-occurrence tie-break)
    __shared__ double s_val[256];
    __shared__ int    s_idx[256];
    s_val[t] = sc; s_idx[t] = n;
    __syncthreads();
    for (int s = 128; s > 0; s >>= 1) {
        if (t < s) {
            double v2 = s_val[t+s]; int i2 = s_idx[t+s];
            if (v2 > s_val[t] || (v2 == s_val[t] && i2 < s_idx[t])) {
                s_val[t] = v2; s_idx[t] = i2;
            }
        }
        __syncthreads();
    }
    if (t == 0) {
        bmaxv[(size_t)b*NBX + blockIdx.x] = s_val[0];
        bmaxi[(size_t)b*NBX + blockIdx.x] = s_idx[0];
    }
}

// Phase 2: grid (C, B), 256 threads; block owns (b,c):
// wsum[b][c] = sum_n sim[b][n] * x[b][c][n]   (fp64, no atomics)
__global__ void phase2_kernel(const float* __restrict__ x,
                              const double* __restrict__ simbuf,
                              double* __restrict__ wsum)
{
    const int b = blockIdx.y;
    const int c = blockIdx.x;
    const int t = threadIdx.x;

    const float*  xr = x + (size_t)b*CC*NN + (size_t)c*NN;
    const double* sr = simbuf + (size_t)b*NN;

    double acc = 0.0;
    #pragma unroll 4
    for (int n = t; n < NN; n += 256)
        acc = fma(sr[n], (double)xr[n], acc);

    __shared__ double s_red[256];
    s_red[t] = acc;
    __syncthreads();
    for (int s = 128; s > 0; s >>= 1) {
        if (t < s) s_red[t] += s_red[t+s];
        __syncthreads();
    }
    if (t == 0) wsum[(size_t)b*CC + c] = s_red[0];
}

extern "C" void kernel_launch(void* const* d_in, const int* in_sizes, int n_in,
                              void* d_out, int out_size, void* d_ws, size_t ws_size,
                              hipStream_t stream)
{
    const float* x = (const float*)d_in[0];
    // d_in[1] (prior) is provably unused: ind at i==0 is forced to N/2 and
    // score is overwritten with (1 - sim) at i==0, discarding the prior.
    // d_in[2] (nbVec) fixed at 16 by the problem shapes.
    float* out = (float*)d_out;

    char* ws = (char*)d_ws;
    double* score  = (double*)(ws);
    double* simbuf = (double*)(ws + 1048576);
    double* d2part = (double*)(ws + 2097152);
    double* wsum   = (double*)(ws + 6291456);
    double* sumSim = (double*)(ws + 6307840);
    float*  rv     = (float*) (ws + 6307904);
    double* bmaxv  = (double*)(ws + 6316096);
    int*    bmaxi  = (int*)   (ws + 6320192);

    // d_out/d_ws are poisoned before every launch: zero what we accumulate into.
    float* out_selpos = out + (size_t)NBVEC*BB*CC + (size_t)NBVEC*BB*NN;
    hipMemsetAsync(out_selpos, 0, (size_t)BB*NN*sizeof(float), stream);
    hipMemsetAsync(sumSim, 0, BB*sizeof(double), stream);

    for (int i = 0; i <= NBVEC; ++i) {
        control_kernel<<<BB, 256, 0, stream>>>(x, out, bmaxv, bmaxi, wsum, sumSim, rv, i);
        if (i < NBVEC) {
            phase1_kernel<<<dim3(NN/256, CSPLIT, BB), 256, 0, stream>>>(x, rv, d2part);
            finish_kernel<<<dim3(NN/256, BB), 256, 0, stream>>>(
                out, score, simbuf, d2part, sumSim, bmaxv, bmaxi, i);
            phase2_kernel<<<dim3(CC, BB), 256, 0, stream>>>(x, simbuf, wsum);
        }
    }
}